// Round 11
// baseline (297.390 us; speedup 1.0000x reference)
//
#include <hip/hip_runtime.h>

typedef __attribute__((ext_vector_type(8))) short s8v;   // 8 x bf16 (4 VGPRs)
typedef __attribute__((ext_vector_type(4))) short s4v;   // 4 x bf16
typedef __attribute__((ext_vector_type(4))) float f4v;   // 4 x f32

#define MFMA16(a, b, c) __builtin_amdgcn_mfma_f32_16x16x32_bf16((a), (b), (c), 0, 0, 0)

// ---- problem constants ----
#define NAG   4096
#define SDIM  64
#define DMOD  128
#define NHD   4
#define DKD   32
#define HIDD  256
static constexpr float INV_SCALE = 0.17677669529663687f;   // 1/sqrt(32)
static constexpr float EPSV = 1e-5f;

// ---- output offsets (floats) ----
#define OFF_ACT   0
#define OFF_VAL   131072
#define OFF_MSG   135168
#define OFF_TASK  266240
#define OFF_ATTN  397312
#define OFF_GOBJ  67506176

// ---- workspace offsets (bytes) ----
static constexpr size_t WS_P1   = 0;          // 512*256*4
static constexpr size_t WS_P1B  = 524288;     // 16*256*4
static constexpr size_t WS_P2   = 540672;     // 16*256*4
static constexpr size_t WS_TACT = 558080;     // 4096*128*4
static constexpr size_t WS_Q    = 2655232;    // 4*4096*32*2 (bf16, pre-scaled)
static constexpr size_t WS_K    = 3703808;    // 4*4096*32*2
static constexpr size_t WS_VT   = 4752384;    // 4*32*4096*2 (transposed)
static constexpr size_t WS_CTX  = 5800960;    // 4096*128*4
static constexpr size_t WS_OPIN = 7898112;    // 4096*224*2
static constexpr size_t WS_H    = 9733120;    // 4096*256*2
static constexpr size_t WS_OPF  = 11830272;   // 4096*128*2 (unused now)
static constexpr size_t WS_OW1T = 12878848;   // 256*224*2
static constexpr size_t WS_OW2T = 12993536;   // 128*256*2
// end ~ 13.06 MB

typedef unsigned short u16;
typedef unsigned int   u32;

static __device__ __forceinline__ u16 f2bf(float f) {
    union { float f; u32 u; } x; x.f = f;
    u32 r = x.u + 0x7FFFu + ((x.u >> 16) & 1u);   // RNE (finite data)
    return (u16)(r >> 16);
}
static __device__ __forceinline__ float bf2f(u16 b) {
    union { u32 u; float f; } x; x.u = ((u32)b) << 16;
    return x.f;
}

// ======================= K1: gs @ sw1 partials (268MB stream) + fused weight prep =======================
__global__ __launch_bounds__(256) void k1_sw1(const float* __restrict__ gs,
                                              const float* __restrict__ sw1,
                                              float* __restrict__ p1,
                                              const float* __restrict__ ow1,
                                              const float* __restrict__ ow2,
                                              u16* __restrict__ w1t,
                                              u16* __restrict__ w2t) {
    int tid = threadIdx.x;
    int b = blockIdx.x;
    if (b >= 512) {
        int bb = b - 512;
        if (bb < 224) {
            // ow1 [224][256] -> w1t [256][224]; block bb = source row k
            w1t[tid * 224 + bb] = f2bf(ow1[bb * 256 + tid]);
        } else if (tid < 128) {
            // ow2 [256][128] -> w2t [128][256]; 32 blocks x 8 source rows
            int k0 = (bb - 224) * 8;
#pragma unroll
            for (int kk = 0; kk < 8; ++kk) {
                int k = k0 + kk;
                w2t[tid * 256 + k] = f2bf(ow2[k * 128 + tid]);
            }
        }
        return;
    }
    __shared__ float gsl[512];
    __shared__ float red[4][256];
    gsl[tid]       = gs[b * 512 + tid];
    gsl[tid + 256] = gs[b * 512 + 256 + tid];
    __syncthreads();
    int t = tid & 63;      // column quad
    int rg = tid >> 6;     // row group 0..3
    const f4v* w4 = (const f4v*)sw1;
    f4v acc = {0.f, 0.f, 0.f, 0.f};
    size_t rb = (size_t)b * 512;
#pragma unroll 4
    for (int r = rg; r < 512; r += 4) {
        float g = gsl[r];
        f4v w = __builtin_nontemporal_load(&w4[(rb + r) * 64 + t]);
        acc[0] += g * w[0]; acc[1] += g * w[1]; acc[2] += g * w[2]; acc[3] += g * w[3];
    }
    red[rg][4 * t + 0] = acc[0]; red[rg][4 * t + 1] = acc[1];
    red[rg][4 * t + 2] = acc[2]; red[rg][4 * t + 3] = acc[3];
    __syncthreads();
    float s = red[0][tid] + red[1][tid] + red[2][tid] + red[3][tid];
    p1[b * 256 + tid] = s;
}

// ======================= K1b: reduce 512 -> 16 partials =======================
__global__ void k1b_red(const float* __restrict__ p1, float* __restrict__ p1b) {
    int j = threadIdx.x;
    int b0 = blockIdx.x * 32;
    float s = 0.f;
#pragma unroll
    for (int b = 0; b < 32; ++b) s += p1[(b0 + b) * 256 + j];
    p1b[blockIdx.x * 256 + j] = s;
}

// ======================= K2b: h1 + strat partials =======================
__global__ void k2b_strat(const float* __restrict__ p1b, const float* __restrict__ sb1,
                          const float* __restrict__ sw2, float* __restrict__ p2) {
    __shared__ float h1[256];
    int j = threadIdx.x;
    float s = 0.f;
#pragma unroll
    for (int b = 0; b < 16; ++b) s += p1b[b * 256 + j];
    h1[j] = fmaxf(s + sb1[j], 0.f);
    __syncthreads();
    int i0 = blockIdx.x * 16;
    float acc = 0.f;
#pragma unroll
    for (int i = 0; i < 16; ++i) acc += h1[i0 + i] * sw2[(i0 + i) * 256 + j];
    p2[blockIdx.x * 256 + j] = acc;
}

// ======================= K3: strat+gobj + tact + QKV (512 blocks x 8 agents) =======================
__global__ __launch_bounds__(256) void k3_tact_qkv(
    const float* __restrict__ p2, const float* __restrict__ sb2,
    const float* __restrict__ sow, const float* __restrict__ sob,
    const float* __restrict__ as, const float* __restrict__ tw, const float* __restrict__ tb,
    const float* __restrict__ wq, const float* __restrict__ bq,
    const float* __restrict__ wk, const float* __restrict__ bk,
    const float* __restrict__ wv, const float* __restrict__ bv,
    float* __restrict__ out_gobj, float* __restrict__ tactws,
    u16* __restrict__ qws, u16* __restrict__ kws, u16* __restrict__ vtws) {
    __shared__ float strat[256];
    __shared__ float gobj[64];
    __shared__ float asl[8][64];
    __shared__ float tl[8][128];
    int tid = threadIdx.x;
    int a0 = blockIdx.x * 8;
    { // strat
        float s = 0.f;
#pragma unroll
        for (int b = 0; b < 16; ++b) s += p2[b * 256 + tid];
        strat[tid] = fmaxf(s + sb2[tid], 0.f);
    }
    // stage agent states rows (8 agents x 64)
#pragma unroll
    for (int r = 0; r < 2; ++r) {
        int idx = tid + r * 256;
        asl[idx >> 6][idx & 63] = as[a0 * 64 + idx];
    }
    __syncthreads();
    if (tid < 64) {
        float g = sob[tid];
        for (int i = 0; i < 256; ++i) g += strat[i] * sow[i * 64 + tid];
        gobj[tid] = g;
        if (blockIdx.x == 0) out_gobj[tid] = g;
    }
    __syncthreads();
    int ah = tid >> 7, j = tid & 127;   // ah selects agent half (4 agents each)
    // tact
    float gacc = 0.f;
    for (int i = 0; i < 64; ++i) gacc += gobj[i] * tw[(64 + i) * 128 + j];
    float acc[4];
    float base = tb[j] + gacc;
#pragma unroll
    for (int a = 0; a < 4; ++a) acc[a] = base;
    for (int i = 0; i < 64; ++i) {
        float w = tw[i * 128 + j];
#pragma unroll
        for (int a = 0; a < 4; ++a) acc[a] += asl[ah * 4 + a][i] * w;
    }
#pragma unroll
    for (int a = 0; a < 4; ++a) {
        float t = fmaxf(acc[a], 0.f);
        tl[ah * 4 + a][j] = t;
        tactws[(size_t)(a0 + ah * 4 + a) * 128 + j] = t;
    }
    __syncthreads();
    int h = j >> 5, d = j & 31;
    // q
#pragma unroll
    for (int a = 0; a < 4; ++a) acc[a] = 0.f;
    for (int i = 0; i < 128; ++i) {
        float w = wq[i * 128 + j];
#pragma unroll
        for (int a = 0; a < 4; ++a) acc[a] += tl[ah * 4 + a][i] * w;
    }
#pragma unroll
    for (int a = 0; a < 4; ++a)
        qws[h * 131072 + (a0 + ah * 4 + a) * 32 + d] = f2bf((acc[a] + bq[j]) * INV_SCALE);
    // k
#pragma unroll
    for (int a = 0; a < 4; ++a) acc[a] = 0.f;
    for (int i = 0; i < 128; ++i) {
        float w = wk[i * 128 + j];
#pragma unroll
        for (int a = 0; a < 4; ++a) acc[a] += tl[ah * 4 + a][i] * w;
    }
#pragma unroll
    for (int a = 0; a < 4; ++a)
        kws[h * 131072 + (a0 + ah * 4 + a) * 32 + d] = f2bf(acc[a] + bk[j]);
    // v -> transposed [h][d][n], packed 4 agents
#pragma unroll
    for (int a = 0; a < 4; ++a) acc[a] = 0.f;
    for (int i = 0; i < 128; ++i) {
        float w = wv[i * 128 + j];
#pragma unroll
        for (int a = 0; a < 4; ++a) acc[a] += tl[ah * 4 + a][i] * w;
    }
    union { u16 u[4]; s4v v; } pk;
#pragma unroll
    for (int a = 0; a < 4; ++a) pk.u[a] = f2bf(acc[a] + bv[j]);
    *(s4v*)(vtws + h * 131072 + d * 4096 + a0 + ah * 4) = pk.v;
}

// ======================= K4: fused attention v10 (unchanged from R10) =======================
__global__ __launch_bounds__(512) void k4_attn(
    const u16* __restrict__ qws, const u16* __restrict__ kws, const u16* __restrict__ vtws,
    float* __restrict__ attn, float* __restrict__ ctxws) {
    int tid = threadIdx.x;
    int wid = tid >> 6;      // wave 0..7
    int l = tid & 63;
    int g = l >> 4;
    int ln = l & 15;
    int h = blockIdx.x >> 8;
    int qt = (blockIdx.x & 255) * 16;
    const u16* qh = qws + h * 131072;
    const u16* kh = kws + h * 131072;
    const u16* vh = vtws + h * 131072;
    int j0 = wid * 512;

    s8v aq = *(const s8v*)(qh + (qt + ln) * 32 + 8 * g);
    f4v zero = {0.f, 0.f, 0.f, 0.f};

    __shared__ __align__(16) union SmemU {
        struct {
            float red[8][16];                 // [wave][qrow] partial row sums
            u16 ldsPb[8][2][16][40];          // wave-private bf16 P (PV roundtrip)
            float pctx[8][16][32];            // [wave][q][d] partial ctx
        } a;                                  // 37376 B
        float sT[2][16][260];                 // 2 x 16 q-rows x 256 cols (+4 pad)
    } sm;

    // ---- sweep 1: unnormalized PV + row sums over this wave's eighth ----
    f4v lacc = zero, accA = zero, accB = zero;
    int buf = 0;
    for (int jc = 0; jc < 16; ++jc) {
        int jb = j0 + jc * 32;
        s8v b0 = *(const s8v*)(kh + (jb + ln) * 32 + 8 * g);
        s8v b1 = *(const s8v*)(kh + (jb + 16 + ln) * 32 + 8 * g);
        f4v S0 = MFMA16(aq, b0, zero);
        f4v S1 = MFMA16(aq, b1, zero);
#pragma unroll
        for (int r = 0; r < 4; ++r) {
            float w0 = __expf(S0[r]);
            float w1 = __expf(S1[r]);
            lacc[r] += w0 + w1;
            sm.a.ldsPb[wid][buf][4 * g + r][ln] = f2bf(w0);
            sm.a.ldsPb[wid][buf][4 * g + r][16 + ln] = f2bf(w1);
        }
        s8v bp = *(const s8v*)&sm.a.ldsPb[wid][buf][ln][8 * g];
        s8v va = *(const s8v*)(vh + ln * 4096 + jb + 8 * g);
        s8v vb = *(const s8v*)(vh + (16 + ln) * 4096 + jb + 8 * g);
        accA = MFMA16(va, bp, accA);
        accB = MFMA16(vb, bp, accB);
        buf ^= 1;
    }
#pragma unroll
    for (int m = 1; m <= 8; m <<= 1) {
        lacc[0] += __shfl_xor(lacc[0], m);
        lacc[1] += __shfl_xor(lacc[1], m);
        lacc[2] += __shfl_xor(lacc[2], m);
        lacc[3] += __shfl_xor(lacc[3], m);
    }
    if (ln == 0) {
#pragma unroll
        for (int r = 0; r < 4; ++r) sm.a.red[wid][4 * g + r] = lacc[r];
    }
    __syncthreads();
    float linvq = 1.f / (sm.a.red[0][ln] + sm.a.red[1][ln] + sm.a.red[2][ln] + sm.a.red[3][ln] +
                         sm.a.red[4][ln] + sm.a.red[5][ln] + sm.a.red[6][ln] + sm.a.red[7][ln]);
#pragma unroll
    for (int r = 0; r < 4; ++r) {
        sm.a.pctx[wid][ln][4 * g + r] = accA[r] * linvq;
        sm.a.pctx[wid][ln][16 + 4 * g + r] = accB[r] * linvq;
    }
    __syncthreads();
    {
        int q = tid >> 5;          // 0..15
        int d = tid & 31;          // 0..31
        float s = sm.a.pctx[0][q][d] + sm.a.pctx[1][q][d] + sm.a.pctx[2][q][d] + sm.a.pctx[3][q][d] +
                  sm.a.pctx[4][q][d] + sm.a.pctx[5][q][d] + sm.a.pctx[6][q][d] + sm.a.pctx[7][q][d];
        ctxws[(size_t)(qt + q) * 128 + h * 32 + d] = s;
    }
    __syncthreads();   // pctx reads done; union may now be reused as sT

    // ---- sweep 2: dbuf LDS transpose -> whole-row contiguous stores ----
    float* attnh = attn + (size_t)h * 4096 * 4096;
    auto COMPUTE = [&](int c, int p) {
        int co = wid * 32;
        int jb = c * 256 + co;
        s8v b0 = *(const s8v*)(kh + (jb + ln) * 32 + 8 * g);
        s8v b1 = *(const s8v*)(kh + (jb + 16 + ln) * 32 + 8 * g);
        f4v S0 = MFMA16(b0, aq, zero);
        f4v S1 = MFMA16(b1, aq, zero);
        f4v o0, o1;
#pragma unroll
        for (int r = 0; r < 4; ++r) {
            o0[r] = __expf(S0[r]) * linvq;
            o1[r] = __expf(S1[r]) * linvq;
        }
        *(f4v*)&sm.sT[p][ln][co + 4 * g] = o0;
        *(f4v*)&sm.sT[p][ln][co + 16 + 4 * g] = o1;
    };
    auto STORE = [&](int c, int p) {
#pragma unroll
        for (int r2 = 0; r2 < 2; ++r2) {
            int row = 2 * wid + r2;
            f4v t = *(const f4v*)&sm.sT[p][row][4 * l];
            *(f4v*)(attnh + (size_t)(qt + row) * 4096 + c * 256 + 4 * l) = t;
        }
    };
    COMPUTE(0, 0);
    __syncthreads();
    for (int c = 1; c < 16; ++c) {
        STORE(c - 1, (c - 1) & 1);
        COMPUTE(c, c & 1);
        __syncthreads();
    }
    STORE(15, 1);
}

// ======================= K5: wo + LayerNorm + task + op_in (L2 weights, barrier-free) =======================
__global__ __launch_bounds__(512) void k5_post(
    const float* __restrict__ ctxws, const float* __restrict__ tactws,
    const float* __restrict__ wo, const float* __restrict__ bo,
    const float* __restrict__ lng, const float* __restrict__ lnb,
    const float* __restrict__ taw1, const float* __restrict__ tab1,
    const float* __restrict__ taw2, const float* __restrict__ tab2,
    const float* __restrict__ as, float* __restrict__ dout, u16* __restrict__ opin) {
    // all LDS is wave-private scratch -> no __syncthreads needed anywhere
    __shared__ float cx[8][128];
    __shared__ float coords[8][128];
    __shared__ float t1v[8][64];
    int tid = threadIdx.x;
    int w = tid >> 6, l = tid & 63;
    for (int it = 0; it < 2; ++it) {
        int n = blockIdx.x * 16 + w * 2 + it;
        float c0 = ctxws[(size_t)n * 128 + l], c1 = ctxws[(size_t)n * 128 + 64 + l];
        float t0 = tactws[(size_t)n * 128 + l], t1 = tactws[(size_t)n * 128 + 64 + l];
        float av = as[n * 64 + l];
        cx[w][l] = c0; cx[w][64 + l] = c1;
        float r0 = bo[l] + t0, r1 = bo[64 + l] + t1;
        for (int k = 0; k < 128; ++k) {
            float cv = cx[w][k];
            r0 += cv * wo[k * 128 + l];
            r1 += cv * wo[k * 128 + 64 + l];
        }
        float s = r0 + r1;
#pragma unroll
        for (int m = 1; m <= 32; m <<= 1) s += __shfl_xor(s, m);
        float mu = s * (1.f / 128.f);
        float d0 = r0 - mu, d1 = r1 - mu;
        float vs = d0 * d0 + d1 * d1;
#pragma unroll
        for (int m = 1; m <= 32; m <<= 1) vs += __shfl_xor(vs, m);
        float rstd = 1.f / sqrtf(vs * (1.f / 128.f) + EPSV);
        float co0 = d0 * rstd * lng[l] + lnb[l];
        float co1 = d1 * rstd * lng[64 + l] + lnb[64 + l];
        coords[w][l] = co0; coords[w][64 + l] = co1;
        opin[(size_t)n * 224 + l] = f2bf(av);
        opin[(size_t)n * 224 + 64 + l] = f2bf(co0);
        opin[(size_t)n * 224 + 128 + l] = f2bf(co1);
        float a1 = tab1[l];
        for (int i = 0; i < 128; ++i) a1 += coords[w][i] * taw1[i * 64 + l];
        t1v[w][l] = fmaxf(a1, 0.f);
        if (l < 32) {
            float a2 = tab2[l];
            for (int i = 0; i < 64; ++i) a2 += t1v[w][i] * taw2[i * 32 + l];
            float mx = a2;
#pragma unroll
            for (int m = 1; m <= 16; m <<= 1) mx = fmaxf(mx, __shfl_xor(mx, m));
            float e = __expf(a2 - mx);
            float se = e;
#pragma unroll
            for (int m = 1; m <= 16; m <<= 1) se += __shfl_xor(se, m);
            float tk = e / se;
            dout[OFF_TASK + n * 32 + l] = tk;
            opin[(size_t)n * 224 + 192 + l] = f2bf(tk);
        }
    }
}

// ======================= K6a: H = relu(opin @ ow1 + ob1), bf16 MFMA =======================
__global__ __launch_bounds__(256) void k6a(const u16* __restrict__ opin, const u16* __restrict__ w1t,
                                           const float* __restrict__ ob1, u16* __restrict__ Hws) {
    int tid = threadIdx.x;
    int w = tid >> 6, l = tid & 63, g = l >> 4, ln = l & 15;
    int bm = blockIdx.x & 63, bn = blockIdx.x >> 6;
    int m0 = bm * 64 + w * 16, n0 = bn * 64;
    f4v acc[4];
    f4v zero = {0.f, 0.f, 0.f, 0.f};
#pragma unroll
    for (int nt = 0; nt < 4; ++nt) acc[nt] = zero;
    for (int kt = 0; kt < 7; ++kt) {
        s8v A = *(const s8v*)(opin + (size_t)(m0 + ln) * 224 + kt * 32 + 8 * g);
#pragma unroll
        for (int nt = 0; nt < 4; ++nt) {
            s8v B = *(const s8v*)(w1t + (size_t)(n0 + nt * 16 + ln) * 224 + kt * 32 + 8 * g);
            acc[nt] = MFMA16(A, B, acc[nt]);
        }
    }
#pragma unroll
    for (int nt = 0; nt < 4; ++nt) {
        int col = n0 + nt * 16 + ln;
        float bias = ob1[col];
#pragma unroll
        for (int r = 0; r < 4; ++r) {
            int row = m0 + 4 * g + r;
            Hws[(size_t)row * 256 + col] = f2bf(fmaxf(acc[nt][r] + bias, 0.f));
        }
    }
}

// ======================= K6bc: opf (MFMA) + actions/values/messages, fused =======================
// grid 64; block handles 64 rows (full 128 opf cols), opf kept in LDS.
__global__ __launch_bounds__(256) void k6bc(const u16* __restrict__ Hws, const u16* __restrict__ w2t,
                                            const float* __restrict__ ob2, const float* __restrict__ as,
                                            const float* __restrict__ aw, const float* __restrict__ ab,
                                            const float* __restrict__ vw, const float* __restrict__ vb,
                                            const float* __restrict__ cw, const float* __restrict__ cb,
                                            const float* __restrict__ cdw, const float* __restrict__ cdb,
                                            float* __restrict__ dout) {
    __shared__ float opfs[64][128];
    __shared__ float asl[64][64];
    __shared__ float m1s[64][64];
    int tid = threadIdx.x;
    int w = tid >> 6, l = tid & 63, g = l >> 4, ln = l & 15;
    int m0 = blockIdx.x * 64;
    int mw = m0 + w * 16;
    // stage agent states (64 rows x 64)
    for (int i = tid; i < 64 * 64; i += 256) asl[i >> 6][i & 63] = as[m0 * 64 + i];
    // opf = relu(H @ w2t + ob2): wave w rows mw..+16, all 128 cols
    f4v acc[8];
    f4v zero = {0.f, 0.f, 0.f, 0.f};
#pragma unroll
    for (int nt = 0; nt < 8; ++nt) acc[nt] = zero;
    for (int kt = 0; kt < 8; ++kt) {
        s8v A = *(const s8v*)(Hws + (size_t)(mw + ln) * 256 + kt * 32 + 8 * g);
#pragma unroll
        for (int nt = 0; nt < 8; ++nt) {
            s8v B = *(const s8v*)(w2t + (size_t)(nt * 16 + ln) * 256 + kt * 32 + 8 * g);
            acc[nt] = MFMA16(A, B, acc[nt]);
        }
    }
#pragma unroll
    for (int nt = 0; nt < 8; ++nt) {
        int col = nt * 16 + ln;
        float bias = ob2[col];
#pragma unroll
        for (int r = 0; r < 4; ++r)
            opfs[w * 16 + 4 * g + r][col] = fmaxf(acc[nt][r] + bias, 0.f);
    }
    __syncthreads();
    // actions: thread: col c = tid&31, rows r0 = (tid>>5)*8 .. +8
    {
        int c = tid & 31;
        int r0 = (tid >> 5) * 8;
        float o[8];
#pragma unroll
        for (int r = 0; r < 8; ++r) o[r] = ab[c];
        for (int k = 0; k < 128; ++k) {
            float wv_ = aw[k * 32 + c];
#pragma unroll
            for (int r = 0; r < 8; ++r) o[r] += opfs[r0 + r][k] * wv_;
        }
#pragma unroll
        for (int r = 0; r < 8; ++r) dout[OFF_ACT + (m0 + r0 + r) * 32 + c] = o[r];
    }
    // values: thread: row r = tid>>2, quarter q = tid&3
    {
        int r = tid >> 2, q = tid & 3;
        float p = 0.f;
        for (int k = q * 32; k < q * 32 + 32; ++k) p += opfs[r][k] * vw[k];
        p += __shfl_xor(p, 1);
        p += __shfl_xor(p, 2);
        if (q == 0) dout[OFF_VAL + m0 + r] = p + vb[0];
    }
    // messages stage 1: m1[r][j] = cb[j] + as_row . cw_col
    {
        int j = tid & 63;
        int r0 = (tid >> 6) * 16;
        float mo[16];
#pragma unroll
        for (int r = 0; r < 16; ++r) mo[r] = cb[j];
        for (int k = 0; k < 64; ++k) {
            float wv_ = cw[k * 64 + j];
#pragma unroll
            for (int r = 0; r < 16; ++r) mo[r] += asl[r0 + r][k] * wv_;
        }
#pragma unroll
        for (int r = 0; r < 16; ++r) m1s[r0 + r][j] = mo[r];
    }
    __syncthreads();
    // messages stage 2
    {
        int c = tid & 31;
        int r0 = (tid >> 5) * 8;
        float o[8];
#pragma unroll
        for (int r = 0; r < 8; ++r) o[r] = cdb[c];
        for (int k = 0; k < 64; ++k) {
            float wv_ = cdw[k * 32 + c];
#pragma unroll
            for (int r = 0; r < 8; ++r) o[r] += m1s[r0 + r][k] * wv_;
        }
#pragma unroll
        for (int r = 0; r < 8; ++r) dout[OFF_MSG + (m0 + r0 + r) * 32 + c] = o[r];
    }
}

// ======================= launch =======================
extern "C" void kernel_launch(void* const* d_in, const int* in_sizes, int n_in,
                              void* d_out, int out_size, void* d_ws, size_t ws_size,
                              hipStream_t stream) {
    const float* as  = (const float*)d_in[0];
    const float* sw1 = (const float*)d_in[1];
    const float* sb1 = (const float*)d_in[2];
    const float* sw2 = (const float*)d_in[3];
    const float* sb2 = (const float*)d_in[4];
    const float* sow = (const float*)d_in[5];
    const float* sob = (const float*)d_in[6];
    const float* tw  = (const float*)d_in[7];
    const float* tb  = (const float*)d_in[8];
    const float* wq  = (const float*)d_in[9];
    const float* bq  = (const float*)d_in[10];
    const float* wk  = (const float*)d_in[11];
    const float* bk  = (const float*)d_in[12];
    const float* wv  = (const float*)d_in[13];
    const float* bv  = (const float*)d_in[14];
    const float* wo  = (const float*)d_in[15];
    const float* bo  = (const float*)d_in[16];
    const float* lng = (const float*)d_in[17];
    const float* lnb = (const float*)d_in[18];
    const float* taw1 = (const float*)d_in[19];
    const float* tab1 = (const float*)d_in[20];
    const float* taw2 = (const float*)d_in[21];
    const float* tab2 = (const float*)d_in[22];
    const float* ow1 = (const float*)d_in[23];
    const float* ob1 = (const float*)d_in[24];
    const float* ow2 = (const float*)d_in[25];
    const float* ob2 = (const float*)d_in[26];
    const float* aw  = (const float*)d_in[27];
    const float* ab  = (const float*)d_in[28];
    const float* vw  = (const float*)d_in[29];
    const float* vb  = (const float*)d_in[30];
    const float* cw  = (const float*)d_in[31];
    const float* cb  = (const float*)d_in[32];
    const float* cdw = (const float*)d_in[33];
    const float* cdb = (const float*)d_in[34];

    float* dout = (float*)d_out;
    char* ws = (char*)d_ws;
    float* p1    = (float*)(ws + WS_P1);
    float* p1b   = (float*)(ws + WS_P1B);
    float* p2    = (float*)(ws + WS_P2);
    float* tactw = (float*)(ws + WS_TACT);
    u16*   qws   = (u16*)(ws + WS_Q);
    u16*   kws   = (u16*)(ws + WS_K);
    u16*   vtws  = (u16*)(ws + WS_VT);
    float* ctxws = (float*)(ws + WS_CTX);
    u16*   opin  = (u16*)(ws + WS_OPIN);
    u16*   Hws   = (u16*)(ws + WS_H);
    u16*   w1t   = (u16*)(ws + WS_OW1T);
    u16*   w2t   = (u16*)(ws + WS_OW2T);

    hipLaunchKernelGGL(k1_sw1, dim3(768), dim3(256), 0, stream, as, sw1, p1, ow1, ow2, w1t, w2t);
    hipLaunchKernelGGL(k1b_red, dim3(16), dim3(256), 0, stream, p1, p1b);
    hipLaunchKernelGGL(k2b_strat, dim3(16), dim3(256), 0, stream, p1b, sb1, sw2, p2);
    hipLaunchKernelGGL(k3_tact_qkv, dim3(512), dim3(256), 0, stream,
                       p2, sb2, sow, sob, as, tw, tb, wq, bq, wk, bk, wv, bv,
                       dout + OFF_GOBJ, tactw, qws, kws, vtws);
    hipLaunchKernelGGL(k4_attn, dim3(1024), dim3(512), 0, stream,
                       qws, kws, vtws, dout + OFF_ATTN, ctxws);
    hipLaunchKernelGGL(k5_post, dim3(256), dim3(512), 0, stream,
                       ctxws, tactw, wo, bo, lng, lnb, taw1, tab1, taw2, tab2, as, dout, opin);
    hipLaunchKernelGGL(k6a, dim3(256), dim3(256), 0, stream, opin, w1t, ob1, Hws);
    hipLaunchKernelGGL(k6bc, dim3(64), dim3(256), 0, stream,
                       Hws, w2t, ob2, as, aw, ab, vw, vb, cw, cb, cdw, cdb, dout);
}

// Round 12
// 193.379 us; speedup vs baseline: 1.5379x; 1.5379x over previous
//
#include <hip/hip_runtime.h>

typedef __attribute__((ext_vector_type(8))) short s8v;   // 8 x bf16 (4 VGPRs)
typedef __attribute__((ext_vector_type(4))) short s4v;   // 4 x bf16
typedef __attribute__((ext_vector_type(4))) float f4v;   // 4 x f32

#define MFMA16(a, b, c) __builtin_amdgcn_mfma_f32_16x16x32_bf16((a), (b), (c), 0, 0, 0)

// ---- problem constants ----
#define NAG   4096
#define SDIM  64
#define DMOD  128
#define NHD   4
#define DKD   32
#define HIDD  256
static constexpr float INV_SCALE = 0.17677669529663687f;   // 1/sqrt(32)
static constexpr float EPSV = 1e-5f;

// ---- output offsets (floats) ----
#define OFF_ACT   0
#define OFF_VAL   131072
#define OFF_MSG   135168
#define OFF_TASK  266240
#define OFF_ATTN  397312
#define OFF_GOBJ  67506176

// ---- workspace offsets (bytes) ----
static constexpr size_t WS_P1   = 0;          // 512*256*4
static constexpr size_t WS_P1B  = 524288;     // 16*256*4
static constexpr size_t WS_P2   = 540672;     // 16*256*4
static constexpr size_t WS_TACT = 558080;     // 4096*128*4
static constexpr size_t WS_Q    = 2655232;    // 4*4096*32*2 (bf16, pre-scaled)
static constexpr size_t WS_K    = 3703808;    // 4*4096*32*2
static constexpr size_t WS_VT   = 4752384;    // 4*32*4096*2 (transposed)
static constexpr size_t WS_CTX  = 5800960;    // 4096*128*4
static constexpr size_t WS_OPIN = 7898112;    // 4096*224*2
static constexpr size_t WS_H    = 9733120;    // 4096*256*2
static constexpr size_t WS_OPF  = 11830272;   // 4096*128*2
static constexpr size_t WS_OW1T = 12878848;   // 256*224*2
static constexpr size_t WS_OW2T = 12993536;   // 128*256*2
// end ~ 13.06 MB

typedef unsigned short u16;
typedef unsigned int   u32;

static __device__ __forceinline__ u16 f2bf(float f) {
    union { float f; u32 u; } x; x.f = f;
    u32 r = x.u + 0x7FFFu + ((x.u >> 16) & 1u);   // RNE (finite data)
    return (u16)(r >> 16);
}
static __device__ __forceinline__ float bf2f(u16 b) {
    union { u32 u; float f; } x; x.u = ((u32)b) << 16;
    return x.f;
}

// ======================= K1: gs @ sw1 partials (268MB stream) + fused weight prep =======================
// blocks 0..511: k1 streaming; blocks 512..767: bf16 weight transposes (independent work)
__global__ __launch_bounds__(256) void k1_sw1(const float* __restrict__ gs,
                                              const float* __restrict__ sw1,
                                              float* __restrict__ p1,
                                              const float* __restrict__ ow1,
                                              const float* __restrict__ ow2,
                                              u16* __restrict__ w1t,
                                              u16* __restrict__ w2t) {
    int tid = threadIdx.x;
    int b = blockIdx.x;
    if (b >= 512) {
        int bb = b - 512;
        if (bb < 224) {
            // ow1 [224][256] -> w1t [256][224]; block bb = source row k
            w1t[tid * 224 + bb] = f2bf(ow1[bb * 256 + tid]);
        } else if (tid < 128) {
            // ow2 [256][128] -> w2t [128][256]; 32 blocks x 8 source rows
            int k0 = (bb - 224) * 8;
#pragma unroll
            for (int kk = 0; kk < 8; ++kk) {
                int k = k0 + kk;
                w2t[tid * 256 + k] = f2bf(ow2[k * 128 + tid]);
            }
        }
        return;
    }
    __shared__ float gsl[512];
    __shared__ float red[4][256];
    gsl[tid]       = gs[b * 512 + tid];
    gsl[tid + 256] = gs[b * 512 + 256 + tid];
    __syncthreads();
    int t = tid & 63;      // column quad
    int rg = tid >> 6;     // row group 0..3
    const f4v* w4 = (const f4v*)sw1;
    f4v acc = {0.f, 0.f, 0.f, 0.f};
    size_t rb = (size_t)b * 512;
#pragma unroll 4
    for (int r = rg; r < 512; r += 4) {
        float g = gsl[r];
        f4v w = __builtin_nontemporal_load(&w4[(rb + r) * 64 + t]);
        acc[0] += g * w[0]; acc[1] += g * w[1]; acc[2] += g * w[2]; acc[3] += g * w[3];
    }
    red[rg][4 * t + 0] = acc[0]; red[rg][4 * t + 1] = acc[1];
    red[rg][4 * t + 2] = acc[2]; red[rg][4 * t + 3] = acc[3];
    __syncthreads();
    float s = red[0][tid] + red[1][tid] + red[2][tid] + red[3][tid];
    p1[b * 256 + tid] = s;
}

// ======================= K1b: reduce 512 -> 16 partials =======================
__global__ void k1b_red(const float* __restrict__ p1, float* __restrict__ p1b) {
    int j = threadIdx.x;
    int b0 = blockIdx.x * 32;
    float s = 0.f;
#pragma unroll
    for (int b = 0; b < 32; ++b) s += p1[(b0 + b) * 256 + j];
    p1b[blockIdx.x * 256 + j] = s;
}

// ======================= K2b: h1 + strat partials =======================
__global__ void k2b_strat(const float* __restrict__ p1b, const float* __restrict__ sb1,
                          const float* __restrict__ sw2, float* __restrict__ p2) {
    __shared__ float h1[256];
    int j = threadIdx.x;
    float s = 0.f;
#pragma unroll
    for (int b = 0; b < 16; ++b) s += p1b[b * 256 + j];
    h1[j] = fmaxf(s + sb1[j], 0.f);
    __syncthreads();
    int i0 = blockIdx.x * 16;
    float acc = 0.f;
#pragma unroll
    for (int i = 0; i < 16; ++i) acc += h1[i0 + i] * sw2[(i0 + i) * 256 + j];
    p2[blockIdx.x * 256 + j] = acc;
}

// ======================= K3: strat+gobj + tact + QKV (512 blocks x 8 agents) =======================
__global__ __launch_bounds__(256) void k3_tact_qkv(
    const float* __restrict__ p2, const float* __restrict__ sb2,
    const float* __restrict__ sow, const float* __restrict__ sob,
    const float* __restrict__ as, const float* __restrict__ tw, const float* __restrict__ tb,
    const float* __restrict__ wq, const float* __restrict__ bq,
    const float* __restrict__ wk, const float* __restrict__ bk,
    const float* __restrict__ wv, const float* __restrict__ bv,
    float* __restrict__ out_gobj, float* __restrict__ tactws,
    u16* __restrict__ qws, u16* __restrict__ kws, u16* __restrict__ vtws) {
    __shared__ float strat[256];
    __shared__ float gobj[64];
    __shared__ float asl[8][64];
    __shared__ float tl[8][128];
    int tid = threadIdx.x;
    int a0 = blockIdx.x * 8;
    { // strat
        float s = 0.f;
#pragma unroll
        for (int b = 0; b < 16; ++b) s += p2[b * 256 + tid];
        strat[tid] = fmaxf(s + sb2[tid], 0.f);
    }
    // stage agent states rows (8 agents x 64)
#pragma unroll
    for (int r = 0; r < 2; ++r) {
        int idx = tid + r * 256;
        asl[idx >> 6][idx & 63] = as[a0 * 64 + idx];
    }
    __syncthreads();
    if (tid < 64) {
        float g = sob[tid];
        for (int i = 0; i < 256; ++i) g += strat[i] * sow[i * 64 + tid];
        gobj[tid] = g;
        if (blockIdx.x == 0) out_gobj[tid] = g;
    }
    __syncthreads();
    int ah = tid >> 7, j = tid & 127;   // ah selects agent half (4 agents each)
    // tact
    float gacc = 0.f;
    for (int i = 0; i < 64; ++i) gacc += gobj[i] * tw[(64 + i) * 128 + j];
    float acc[4];
    float base = tb[j] + gacc;
#pragma unroll
    for (int a = 0; a < 4; ++a) acc[a] = base;
    for (int i = 0; i < 64; ++i) {
        float w = tw[i * 128 + j];
#pragma unroll
        for (int a = 0; a < 4; ++a) acc[a] += asl[ah * 4 + a][i] * w;
    }
#pragma unroll
    for (int a = 0; a < 4; ++a) {
        float t = fmaxf(acc[a], 0.f);
        tl[ah * 4 + a][j] = t;
        tactws[(size_t)(a0 + ah * 4 + a) * 128 + j] = t;
    }
    __syncthreads();
    int h = j >> 5, d = j & 31;
    // q
#pragma unroll
    for (int a = 0; a < 4; ++a) acc[a] = 0.f;
    for (int i = 0; i < 128; ++i) {
        float w = wq[i * 128 + j];
#pragma unroll
        for (int a = 0; a < 4; ++a) acc[a] += tl[ah * 4 + a][i] * w;
    }
#pragma unroll
    for (int a = 0; a < 4; ++a)
        qws[h * 131072 + (a0 + ah * 4 + a) * 32 + d] = f2bf((acc[a] + bq[j]) * INV_SCALE);
    // k
#pragma unroll
    for (int a = 0; a < 4; ++a) acc[a] = 0.f;
    for (int i = 0; i < 128; ++i) {
        float w = wk[i * 128 + j];
#pragma unroll
        for (int a = 0; a < 4; ++a) acc[a] += tl[ah * 4 + a][i] * w;
    }
#pragma unroll
    for (int a = 0; a < 4; ++a)
        kws[h * 131072 + (a0 + ah * 4 + a) * 32 + d] = f2bf(acc[a] + bk[j]);
    // v -> transposed [h][d][n], packed 4 agents
#pragma unroll
    for (int a = 0; a < 4; ++a) acc[a] = 0.f;
    for (int i = 0; i < 128; ++i) {
        float w = wv[i * 128 + j];
#pragma unroll
        for (int a = 0; a < 4; ++a) acc[a] += tl[ah * 4 + a][i] * w;
    }
    union { u16 u[4]; s4v v; } pk;
#pragma unroll
    for (int a = 0; a < 4; ++a) pk.u[a] = f2bf(acc[a] + bv[j]);
    *(s4v*)(vtws + h * 131072 + d * 4096 + a0 + ah * 4) = pk.v;
}

// ======================= K4: fused attention v10 (R10, unchanged) =======================
__global__ __launch_bounds__(512) void k4_attn(
    const u16* __restrict__ qws, const u16* __restrict__ kws, const u16* __restrict__ vtws,
    float* __restrict__ attn, float* __restrict__ ctxws) {
    int tid = threadIdx.x;
    int wid = tid >> 6;      // wave 0..7
    int l = tid & 63;
    int g = l >> 4;
    int ln = l & 15;
    int h = blockIdx.x >> 8;
    int qt = (blockIdx.x & 255) * 16;
    const u16* qh = qws + h * 131072;
    const u16* kh = kws + h * 131072;
    const u16* vh = vtws + h * 131072;
    int j0 = wid * 512;

    s8v aq = *(const s8v*)(qh + (qt + ln) * 32 + 8 * g);
    f4v zero = {0.f, 0.f, 0.f, 0.f};

    __shared__ __align__(16) union SmemU {
        struct {
            float red[8][16];                 // [wave][qrow] partial row sums
            u16 ldsPb[8][2][16][40];          // wave-private bf16 P (PV roundtrip)
            float pctx[8][16][32];            // [wave][q][d] partial ctx
        } a;                                  // 37376 B
        float sT[2][16][260];                 // 2 x 16 q-rows x 256 cols (+4 pad)
    } sm;

    // ---- sweep 1: unnormalized PV + row sums over this wave's eighth ----
    f4v lacc = zero, accA = zero, accB = zero;
    int buf = 0;
    for (int jc = 0; jc < 16; ++jc) {
        int jb = j0 + jc * 32;
        s8v b0 = *(const s8v*)(kh + (jb + ln) * 32 + 8 * g);
        s8v b1 = *(const s8v*)(kh + (jb + 16 + ln) * 32 + 8 * g);
        f4v S0 = MFMA16(aq, b0, zero);
        f4v S1 = MFMA16(aq, b1, zero);
#pragma unroll
        for (int r = 0; r < 4; ++r) {
            float w0 = __expf(S0[r]);
            float w1 = __expf(S1[r]);
            lacc[r] += w0 + w1;
            sm.a.ldsPb[wid][buf][4 * g + r][ln] = f2bf(w0);
            sm.a.ldsPb[wid][buf][4 * g + r][16 + ln] = f2bf(w1);
        }
        s8v bp = *(const s8v*)&sm.a.ldsPb[wid][buf][ln][8 * g];
        s8v va = *(const s8v*)(vh + ln * 4096 + jb + 8 * g);
        s8v vb = *(const s8v*)(vh + (16 + ln) * 4096 + jb + 8 * g);
        accA = MFMA16(va, bp, accA);
        accB = MFMA16(vb, bp, accB);
        buf ^= 1;
    }
#pragma unroll
    for (int m = 1; m <= 8; m <<= 1) {
        lacc[0] += __shfl_xor(lacc[0], m);
        lacc[1] += __shfl_xor(lacc[1], m);
        lacc[2] += __shfl_xor(lacc[2], m);
        lacc[3] += __shfl_xor(lacc[3], m);
    }
    if (ln == 0) {
#pragma unroll
        for (int r = 0; r < 4; ++r) sm.a.red[wid][4 * g + r] = lacc[r];
    }
    __syncthreads();
    float linvq = 1.f / (sm.a.red[0][ln] + sm.a.red[1][ln] + sm.a.red[2][ln] + sm.a.red[3][ln] +
                         sm.a.red[4][ln] + sm.a.red[5][ln] + sm.a.red[6][ln] + sm.a.red[7][ln]);
#pragma unroll
    for (int r = 0; r < 4; ++r) {
        sm.a.pctx[wid][ln][4 * g + r] = accA[r] * linvq;
        sm.a.pctx[wid][ln][16 + 4 * g + r] = accB[r] * linvq;
    }
    __syncthreads();
    {
        int q = tid >> 5;          // 0..15
        int d = tid & 31;          // 0..31
        float s = sm.a.pctx[0][q][d] + sm.a.pctx[1][q][d] + sm.a.pctx[2][q][d] + sm.a.pctx[3][q][d] +
                  sm.a.pctx[4][q][d] + sm.a.pctx[5][q][d] + sm.a.pctx[6][q][d] + sm.a.pctx[7][q][d];
        ctxws[(size_t)(qt + q) * 128 + h * 32 + d] = s;
    }
    __syncthreads();   // pctx reads done; union may now be reused as sT

    // ---- sweep 2: dbuf LDS transpose -> whole-row contiguous stores ----
    float* attnh = attn + (size_t)h * 4096 * 4096;
    auto COMPUTE = [&](int c, int p) {
        int co = wid * 32;
        int jb = c * 256 + co;
        s8v b0 = *(const s8v*)(kh + (jb + ln) * 32 + 8 * g);
        s8v b1 = *(const s8v*)(kh + (jb + 16 + ln) * 32 + 8 * g);
        f4v S0 = MFMA16(b0, aq, zero);
        f4v S1 = MFMA16(b1, aq, zero);
        f4v o0, o1;
#pragma unroll
        for (int r = 0; r < 4; ++r) {
            o0[r] = __expf(S0[r]) * linvq;
            o1[r] = __expf(S1[r]) * linvq;
        }
        *(f4v*)&sm.sT[p][ln][co + 4 * g] = o0;
        *(f4v*)&sm.sT[p][ln][co + 16 + 4 * g] = o1;
    };
    auto STORE = [&](int c, int p) {
#pragma unroll
        for (int r2 = 0; r2 < 2; ++r2) {
            int row = 2 * wid + r2;
            f4v t = *(const f4v*)&sm.sT[p][row][4 * l];
            *(f4v*)(attnh + (size_t)(qt + row) * 4096 + c * 256 + 4 * l) = t;
        }
    };
    COMPUTE(0, 0);
    __syncthreads();
    for (int c = 1; c < 16; ++c) {
        STORE(c - 1, (c - 1) & 1);
        COMPUTE(c, c & 1);
        __syncthreads();
    }
    STORE(15, 1);
}

// ======================= K5: wo + LayerNorm + task + op_in (LDS weights; barriers only after staging) =======================
__global__ __launch_bounds__(512) void k5_post(
    const float* __restrict__ ctxws, const float* __restrict__ tactws,
    const float* __restrict__ wo, const float* __restrict__ bo,
    const float* __restrict__ lng, const float* __restrict__ lnb,
    const float* __restrict__ taw1, const float* __restrict__ tab1,
    const float* __restrict__ taw2, const float* __restrict__ tab2,
    const float* __restrict__ as, float* __restrict__ dout, u16* __restrict__ opin) {
    __shared__ float wos[128 * 128];
    __shared__ float tw1s[128 * 64];
    __shared__ float tw2s[64 * 32];
    __shared__ float cx[8][128];       // wave-private
    __shared__ float coords[8][128];   // wave-private
    __shared__ float t1v[8][64];       // wave-private
    int tid = threadIdx.x;
    for (int i = tid; i < 128 * 128; i += 512) wos[i] = wo[i];
    for (int i = tid; i < 128 * 64; i += 512) tw1s[i] = taw1[i];
    for (int i = tid; i < 64 * 32; i += 512) tw2s[i] = taw2[i];
    __syncthreads();   // only barrier: weight staging
    int w = tid >> 6, l = tid & 63;
    for (int it = 0; it < 2; ++it) {
        int n = blockIdx.x * 16 + w * 2 + it;
        float c0 = ctxws[(size_t)n * 128 + l], c1 = ctxws[(size_t)n * 128 + 64 + l];
        float t0 = tactws[(size_t)n * 128 + l], t1 = tactws[(size_t)n * 128 + 64 + l];
        float av = as[n * 64 + l];
        cx[w][l] = c0; cx[w][64 + l] = c1;   // same-wave LDS roundtrip: in-order, no barrier
        float r0 = bo[l] + t0, r1 = bo[64 + l] + t1;
        for (int k = 0; k < 128; ++k) {
            float cv = cx[w][k];
            r0 += cv * wos[k * 128 + l];
            r1 += cv * wos[k * 128 + 64 + l];
        }
        float s = r0 + r1;
#pragma unroll
        for (int m = 1; m <= 32; m <<= 1) s += __shfl_xor(s, m);
        float mu = s * (1.f / 128.f);
        float d0 = r0 - mu, d1 = r1 - mu;
        float vs = d0 * d0 + d1 * d1;
#pragma unroll
        for (int m = 1; m <= 32; m <<= 1) vs += __shfl_xor(vs, m);
        float rstd = 1.f / sqrtf(vs * (1.f / 128.f) + EPSV);
        float co0 = d0 * rstd * lng[l] + lnb[l];
        float co1 = d1 * rstd * lng[64 + l] + lnb[64 + l];
        coords[w][l] = co0; coords[w][64 + l] = co1;
        opin[(size_t)n * 224 + l] = f2bf(av);
        opin[(size_t)n * 224 + 64 + l] = f2bf(co0);
        opin[(size_t)n * 224 + 128 + l] = f2bf(co1);
        float a1 = tab1[l];
        for (int i = 0; i < 128; ++i) a1 += coords[w][i] * tw1s[i * 64 + l];
        t1v[w][l] = fmaxf(a1, 0.f);
        if (l < 32) {
            float a2 = tab2[l];
            for (int i = 0; i < 64; ++i) a2 += t1v[w][i] * tw2s[i * 32 + l];
            float mx = a2;
#pragma unroll
            for (int m = 1; m <= 16; m <<= 1) mx = fmaxf(mx, __shfl_xor(mx, m));
            float e = __expf(a2 - mx);
            float se = e;
#pragma unroll
            for (int m = 1; m <= 16; m <<= 1) se += __shfl_xor(se, m);
            float tk = e / se;
            dout[OFF_TASK + n * 32 + l] = tk;
            opin[(size_t)n * 224 + 192 + l] = f2bf(tk);
        }
    }
}

// ======================= K6a: H = relu(opin @ ow1 + ob1), bf16 MFMA =======================
__global__ __launch_bounds__(256) void k6a(const u16* __restrict__ opin, const u16* __restrict__ w1t,
                                           const float* __restrict__ ob1, u16* __restrict__ Hws) {
    int tid = threadIdx.x;
    int w = tid >> 6, l = tid & 63, g = l >> 4, ln = l & 15;
    int bm = blockIdx.x & 63, bn = blockIdx.x >> 6;
    int m0 = bm * 64 + w * 16, n0 = bn * 64;
    f4v acc[4];
    f4v zero = {0.f, 0.f, 0.f, 0.f};
#pragma unroll
    for (int nt = 0; nt < 4; ++nt) acc[nt] = zero;
    for (int kt = 0; kt < 7; ++kt) {
        s8v A = *(const s8v*)(opin + (size_t)(m0 + ln) * 224 + kt * 32 + 8 * g);
#pragma unroll
        for (int nt = 0; nt < 4; ++nt) {
            s8v B = *(const s8v*)(w1t + (size_t)(n0 + nt * 16 + ln) * 224 + kt * 32 + 8 * g);
            acc[nt] = MFMA16(A, B, acc[nt]);
        }
    }
#pragma unroll
    for (int nt = 0; nt < 4; ++nt) {
        int col = n0 + nt * 16 + ln;
        float bias = ob1[col];
#pragma unroll
        for (int r = 0; r < 4; ++r) {
            int row = m0 + 4 * g + r;
            Hws[(size_t)row * 256 + col] = f2bf(fmaxf(acc[nt][r] + bias, 0.f));
        }
    }
}

// ======================= K6b: opf = relu(H @ ow2 + ob2) =======================
__global__ __launch_bounds__(256) void k6b(const u16* __restrict__ Hws, const u16* __restrict__ w2t,
                                           const float* __restrict__ ob2, u16* __restrict__ opfws) {
    int tid = threadIdx.x;
    int w = tid >> 6, l = tid & 63, g = l >> 4, ln = l & 15;
    int bm = blockIdx.x & 63, bn = blockIdx.x >> 6;
    int m0 = bm * 64 + w * 16, n0 = bn * 64;
    f4v acc[4];
    f4v zero = {0.f, 0.f, 0.f, 0.f};
#pragma unroll
    for (int nt = 0; nt < 4; ++nt) acc[nt] = zero;
    for (int kt = 0; kt < 8; ++kt) {
        s8v A = *(const s8v*)(Hws + (size_t)(m0 + ln) * 256 + kt * 32 + 8 * g);
#pragma unroll
        for (int nt = 0; nt < 4; ++nt) {
            s8v B = *(const s8v*)(w2t + (size_t)(n0 + nt * 16 + ln) * 256 + kt * 32 + 8 * g);
            acc[nt] = MFMA16(A, B, acc[nt]);
        }
    }
#pragma unroll
    for (int nt = 0; nt < 4; ++nt) {
        int col = n0 + nt * 16 + ln;
        float bias = ob2[col];
#pragma unroll
        for (int r = 0; r < 4; ++r) {
            int row = m0 + 4 * g + r;
            opfws[(size_t)row * 128 + col] = f2bf(fmaxf(acc[nt][r] + bias, 0.f));
        }
    }
}

// ======================= K6c: actions / values / messages =======================
__global__ __launch_bounds__(256) void k6c(const u16* __restrict__ opf, const float* __restrict__ as,
                                           const float* __restrict__ aw, const float* __restrict__ ab,
                                           const float* __restrict__ vw, const float* __restrict__ vb,
                                           const float* __restrict__ cw, const float* __restrict__ cb,
                                           const float* __restrict__ cdw, const float* __restrict__ cdb,
                                           float* __restrict__ dout) {
    __shared__ float opfs[4][128];
    __shared__ float asl[4][64];
    __shared__ float m1s[4][64];
    int tid = threadIdx.x;
    int w = tid >> 6, l = tid & 63;
    int n = blockIdx.x * 4 + w;
    {
        u32 u = *(const u32*)(opf + (size_t)n * 128 + 2 * l);
        opfs[w][2 * l] = bf2f((u16)(u & 0xffff));
        opfs[w][2 * l + 1] = bf2f((u16)(u >> 16));
        asl[w][l] = as[n * 64 + l];
    }
    __syncthreads();
    if (l < 32) {
        float a = ab[l];
        for (int k = 0; k < 128; ++k) a += opfs[w][k] * aw[k * 32 + l];
        dout[OFF_ACT + n * 32 + l] = a;
    }
    {
        float p = opfs[w][l] * vw[l] + opfs[w][64 + l] * vw[64 + l];
#pragma unroll
        for (int m = 1; m <= 32; m <<= 1) p += __shfl_xor(p, m);
        if (l == 0) dout[OFF_VAL + n] = p + vb[0];
    }
    {
        float a = cb[l];
        for (int k = 0; k < 64; ++k) a += asl[w][k] * cw[k * 64 + l];
        m1s[w][l] = a;
    }
    __syncthreads();
    if (l < 32) {
        float a = cdb[l];
        for (int k = 0; k < 64; ++k) a += m1s[w][k] * cdw[k * 32 + l];
        dout[OFF_MSG + n * 32 + l] = a;
    }
}

// ======================= launch =======================
extern "C" void kernel_launch(void* const* d_in, const int* in_sizes, int n_in,
                              void* d_out, int out_size, void* d_ws, size_t ws_size,
                              hipStream_t stream) {
    const float* as  = (const float*)d_in[0];
    const float* sw1 = (const float*)d_in[1];
    const float* sb1 = (const float*)d_in[2];
    const float* sw2 = (const float*)d_in[3];
    const float* sb2 = (const float*)d_in[4];
    const float* sow = (const float*)d_in[5];
    const float* sob = (const float*)d_in[6];
    const float* tw  = (const float*)d_in[7];
    const float* tb  = (const float*)d_in[8];
    const float* wq  = (const float*)d_in[9];
    const float* bq  = (const float*)d_in[10];
    const float* wk  = (const float*)d_in[11];
    const float* bk  = (const float*)d_in[12];
    const float* wv  = (const float*)d_in[13];
    const float* bv  = (const float*)d_in[14];
    const float* wo  = (const float*)d_in[15];
    const float* bo  = (const float*)d_in[16];
    const float* lng = (const float*)d_in[17];
    const float* lnb = (const float*)d_in[18];
    const float* taw1 = (const float*)d_in[19];
    const float* tab1 = (const float*)d_in[20];
    const float* taw2 = (const float*)d_in[21];
    const float* tab2 = (const float*)d_in[22];
    const float* ow1 = (const float*)d_in[23];
    const float* ob1 = (const float*)d_in[24];
    const float* ow2 = (const float*)d_in[25];
    const float* ob2 = (const float*)d_in[26];
    const float* aw  = (const float*)d_in[27];
    const float* ab  = (const float*)d_in[28];
    const float* vw  = (const float*)d_in[29];
    const float* vb  = (const float*)d_in[30];
    const float* cw  = (const float*)d_in[31];
    const float* cb  = (const float*)d_in[32];
    const float* cdw = (const float*)d_in[33];
    const float* cdb = (const float*)d_in[34];

    float* dout = (float*)d_out;
    char* ws = (char*)d_ws;
    float* p1    = (float*)(ws + WS_P1);
    float* p1b   = (float*)(ws + WS_P1B);
    float* p2    = (float*)(ws + WS_P2);
    float* tactw = (float*)(ws + WS_TACT);
    u16*   qws   = (u16*)(ws + WS_Q);
    u16*   kws   = (u16*)(ws + WS_K);
    u16*   vtws  = (u16*)(ws + WS_VT);
    float* ctxws = (float*)(ws + WS_CTX);
    u16*   opin  = (u16*)(ws + WS_OPIN);
    u16*   Hws   = (u16*)(ws + WS_H);
    u16*   opfws = (u16*)(ws + WS_OPF);
    u16*   w1t   = (u16*)(ws + WS_OW1T);
    u16*   w2t   = (u16*)(ws + WS_OW2T);

    hipLaunchKernelGGL(k1_sw1, dim3(768), dim3(256), 0, stream, as, sw1, p1, ow1, ow2, w1t, w2t);
    hipLaunchKernelGGL(k1b_red, dim3(16), dim3(256), 0, stream, p1, p1b);
    hipLaunchKernelGGL(k2b_strat, dim3(16), dim3(256), 0, stream, p1b, sb1, sw2, p2);
    hipLaunchKernelGGL(k3_tact_qkv, dim3(512), dim3(256), 0, stream,
                       p2, sb2, sow, sob, as, tw, tb, wq, bq, wk, bk, wv, bv,
                       dout + OFF_GOBJ, tactw, qws, kws, vtws);
    hipLaunchKernelGGL(k4_attn, dim3(1024), dim3(512), 0, stream,
                       qws, kws, vtws, dout + OFF_ATTN, ctxws);
    hipLaunchKernelGGL(k5_post, dim3(256), dim3(512), 0, stream,
                       ctxws, tactw, wo, bo, lng, lnb, taw1, tab1, taw2, tab2, as, dout, opin);
    hipLaunchKernelGGL(k6a, dim3(256), dim3(256), 0, stream, opin, w1t, ob1, Hws);
    hipLaunchKernelGGL(k6b, dim3(128), dim3(256), 0, stream, Hws, w2t, ob2, opfws);
    hipLaunchKernelGGL(k6c, dim3(1024), dim3(256), 0, stream,
                       opfws, as, aw, ab, vw, vb, cw, cb, cdw, cdb, dout);
}

// Round 13
// 190.160 us; speedup vs baseline: 1.5639x; 1.0169x over previous
//
#include <hip/hip_runtime.h>

typedef __attribute__((ext_vector_type(8))) short s8v;   // 8 x bf16 (4 VGPRs)
typedef __attribute__((ext_vector_type(4))) short s4v;   // 4 x bf16
typedef __attribute__((ext_vector_type(4))) float f4v;   // 4 x f32

#define MFMA16(a, b, c) __builtin_amdgcn_mfma_f32_16x16x32_bf16((a), (b), (c), 0, 0, 0)

// ---- problem constants ----
#define NAG   4096
#define SDIM  64
#define DMOD  128
#define NHD   4
#define DKD   32
#define HIDD  256
static constexpr float INV_SCALE = 0.17677669529663687f;   // 1/sqrt(32)
static constexpr float EPSV = 1e-5f;

// ---- output offsets (floats) ----
#define OFF_ACT   0
#define OFF_VAL   131072
#define OFF_MSG   135168
#define OFF_TASK  266240
#define OFF_ATTN  397312
#define OFF_GOBJ  67506176

// ---- workspace offsets (bytes) ----
static constexpr size_t WS_P1   = 0;          // 512*256*4
static constexpr size_t WS_P1B  = 524288;     // 16*256*4
static constexpr size_t WS_P2   = 540672;     // 16*256*4
static constexpr size_t WS_TACT = 558080;     // 4096*128*4
static constexpr size_t WS_Q    = 2655232;    // 4*4096*32*2 (bf16, pre-scaled)
static constexpr size_t WS_K    = 3703808;    // 4*4096*32*2
static constexpr size_t WS_VT   = 4752384;    // 4*32*4096*2 (transposed)
static constexpr size_t WS_CTX  = 5800960;    // 4096*128*4
static constexpr size_t WS_OPIN = 7898112;    // 4096*224*2
static constexpr size_t WS_H    = 9733120;    // 4096*256*2
static constexpr size_t WS_OPF  = 11830272;   // 4096*128*2
static constexpr size_t WS_OW1T = 12878848;   // 256*224*2
static constexpr size_t WS_OW2T = 12993536;   // 128*256*2
// end ~ 13.06 MB

typedef unsigned short u16;
typedef unsigned int   u32;

static __device__ __forceinline__ u16 f2bf(float f) {
    union { float f; u32 u; } x; x.f = f;
    u32 r = x.u + 0x7FFFu + ((x.u >> 16) & 1u);   // RNE (finite data)
    return (u16)(r >> 16);
}
static __device__ __forceinline__ float bf2f(u16 b) {
    union { u32 u; float f; } x; x.u = ((u32)b) << 16;
    return x.f;
}

// ======================= K1: gs @ sw1 partials (268MB stream) + fused weight prep =======================
// blocks 0..511: k1 streaming; blocks 512..767: bf16 weight transposes (independent work)
__global__ __launch_bounds__(256) void k1_sw1(const float* __restrict__ gs,
                                              const float* __restrict__ sw1,
                                              float* __restrict__ p1,
                                              const float* __restrict__ ow1,
                                              const float* __restrict__ ow2,
                                              u16* __restrict__ w1t,
                                              u16* __restrict__ w2t) {
    int tid = threadIdx.x;
    int b = blockIdx.x;
    if (b >= 512) {
        int bb = b - 512;
        if (bb < 224) {
            // ow1 [224][256] -> w1t [256][224]; block bb = source row k
            w1t[tid * 224 + bb] = f2bf(ow1[bb * 256 + tid]);
        } else if (tid < 128) {
            // ow2 [256][128] -> w2t [128][256]; 32 blocks x 8 source rows
            int k0 = (bb - 224) * 8;
#pragma unroll
            for (int kk = 0; kk < 8; ++kk) {
                int k = k0 + kk;
                w2t[tid * 256 + k] = f2bf(ow2[k * 128 + tid]);
            }
        }
        return;
    }
    __shared__ float gsl[512];
    __shared__ float red[4][256];
    gsl[tid]       = gs[b * 512 + tid];
    gsl[tid + 256] = gs[b * 512 + 256 + tid];
    __syncthreads();
    int t = tid & 63;      // column quad
    int rg = tid >> 6;     // row group 0..3
    const f4v* w4 = (const f4v*)sw1;
    f4v acc = {0.f, 0.f, 0.f, 0.f};
    size_t rb = (size_t)b * 512;
#pragma unroll 4
    for (int r = rg; r < 512; r += 4) {
        float g = gsl[r];
        f4v w = __builtin_nontemporal_load(&w4[(rb + r) * 64 + t]);
        acc[0] += g * w[0]; acc[1] += g * w[1]; acc[2] += g * w[2]; acc[3] += g * w[3];
    }
    red[rg][4 * t + 0] = acc[0]; red[rg][4 * t + 1] = acc[1];
    red[rg][4 * t + 2] = acc[2]; red[rg][4 * t + 3] = acc[3];
    __syncthreads();
    float s = red[0][tid] + red[1][tid] + red[2][tid] + red[3][tid];
    p1[b * 256 + tid] = s;
}

// ======================= K1b: reduce 512 -> 16 partials =======================
__global__ void k1b_red(const float* __restrict__ p1, float* __restrict__ p1b) {
    int j = threadIdx.x;
    int b0 = blockIdx.x * 32;
    float s = 0.f;
#pragma unroll
    for (int b = 0; b < 32; ++b) s += p1[(b0 + b) * 256 + j];
    p1b[blockIdx.x * 256 + j] = s;
}

// ======================= K2b: h1 + strat partials =======================
__global__ void k2b_strat(const float* __restrict__ p1b, const float* __restrict__ sb1,
                          const float* __restrict__ sw2, float* __restrict__ p2) {
    __shared__ float h1[256];
    int j = threadIdx.x;
    float s = 0.f;
#pragma unroll
    for (int b = 0; b < 16; ++b) s += p1b[b * 256 + j];
    h1[j] = fmaxf(s + sb1[j], 0.f);
    __syncthreads();
    int i0 = blockIdx.x * 16;
    float acc = 0.f;
#pragma unroll
    for (int i = 0; i < 16; ++i) acc += h1[i0 + i] * sw2[(i0 + i) * 256 + j];
    p2[blockIdx.x * 256 + j] = acc;
}

// ======================= K3: strat+gobj + tact + QKV (512 blocks x 8 agents) =======================
__global__ __launch_bounds__(256) void k3_tact_qkv(
    const float* __restrict__ p2, const float* __restrict__ sb2,
    const float* __restrict__ sow, const float* __restrict__ sob,
    const float* __restrict__ as, const float* __restrict__ tw, const float* __restrict__ tb,
    const float* __restrict__ wq, const float* __restrict__ bq,
    const float* __restrict__ wk, const float* __restrict__ bk,
    const float* __restrict__ wv, const float* __restrict__ bv,
    float* __restrict__ out_gobj, float* __restrict__ tactws,
    u16* __restrict__ qws, u16* __restrict__ kws, u16* __restrict__ vtws) {
    __shared__ float strat[256];
    __shared__ float gobj[64];
    __shared__ float asl[8][64];
    __shared__ float tl[8][128];
    int tid = threadIdx.x;
    int a0 = blockIdx.x * 8;
    { // strat
        float s = 0.f;
#pragma unroll
        for (int b = 0; b < 16; ++b) s += p2[b * 256 + tid];
        strat[tid] = fmaxf(s + sb2[tid], 0.f);
    }
    // stage agent states rows (8 agents x 64)
#pragma unroll
    for (int r = 0; r < 2; ++r) {
        int idx = tid + r * 256;
        asl[idx >> 6][idx & 63] = as[a0 * 64 + idx];
    }
    __syncthreads();
    if (tid < 64) {
        float g = sob[tid];
        for (int i = 0; i < 256; ++i) g += strat[i] * sow[i * 64 + tid];
        gobj[tid] = g;
        if (blockIdx.x == 0) out_gobj[tid] = g;
    }
    __syncthreads();
    int ah = tid >> 7, j = tid & 127;   // ah selects agent half (4 agents each)
    // tact
    float gacc = 0.f;
    for (int i = 0; i < 64; ++i) gacc += gobj[i] * tw[(64 + i) * 128 + j];
    float acc[4];
    float base = tb[j] + gacc;
#pragma unroll
    for (int a = 0; a < 4; ++a) acc[a] = base;
    for (int i = 0; i < 64; ++i) {
        float w = tw[i * 128 + j];
#pragma unroll
        for (int a = 0; a < 4; ++a) acc[a] += asl[ah * 4 + a][i] * w;
    }
#pragma unroll
    for (int a = 0; a < 4; ++a) {
        float t = fmaxf(acc[a], 0.f);
        tl[ah * 4 + a][j] = t;
        tactws[(size_t)(a0 + ah * 4 + a) * 128 + j] = t;
    }
    __syncthreads();
    int h = j >> 5, d = j & 31;
    // q
#pragma unroll
    for (int a = 0; a < 4; ++a) acc[a] = 0.f;
    for (int i = 0; i < 128; ++i) {
        float w = wq[i * 128 + j];
#pragma unroll
        for (int a = 0; a < 4; ++a) acc[a] += tl[ah * 4 + a][i] * w;
    }
#pragma unroll
    for (int a = 0; a < 4; ++a)
        qws[h * 131072 + (a0 + ah * 4 + a) * 32 + d] = f2bf((acc[a] + bq[j]) * INV_SCALE);
    // k
#pragma unroll
    for (int a = 0; a < 4; ++a) acc[a] = 0.f;
    for (int i = 0; i < 128; ++i) {
        float w = wk[i * 128 + j];
#pragma unroll
        for (int a = 0; a < 4; ++a) acc[a] += tl[ah * 4 + a][i] * w;
    }
#pragma unroll
    for (int a = 0; a < 4; ++a)
        kws[h * 131072 + (a0 + ah * 4 + a) * 32 + d] = f2bf(acc[a] + bk[j]);
    // v -> transposed [h][d][n], packed 4 agents
#pragma unroll
    for (int a = 0; a < 4; ++a) acc[a] = 0.f;
    for (int i = 0; i < 128; ++i) {
        float w = wv[i * 128 + j];
#pragma unroll
        for (int a = 0; a < 4; ++a) acc[a] += tl[ah * 4 + a][i] * w;
    }
    union { u16 u[4]; s4v v; } pk;
#pragma unroll
    for (int a = 0; a < 4; ++a) pk.u[a] = f2bf(acc[a] + bv[j]);
    *(s4v*)(vtws + h * 131072 + d * 4096 + a0 + ah * 4) = pk.v;
}

// ======================= K4: fused attention v11 =======================
// 8 waves/block. Pass A: LEAN row sums (QK^T + exp + accumulate; no LDS roundtrip,
// no f2bf, no PV). Pass B: dbuf LDS transpose store pass with PV computed FROM the
// sT tile (2 LDS reads + 8 f2bf + 2 MFMA per chunk, hidden under the store stream).
// PV uses normalized P so ctx needs no final scale.
__global__ __launch_bounds__(512) void k4_attn(
    const u16* __restrict__ qws, const u16* __restrict__ kws, const u16* __restrict__ vtws,
    float* __restrict__ attn, float* __restrict__ ctxws) {
    int tid = threadIdx.x;
    int wid = tid >> 6;      // wave 0..7
    int l = tid & 63;
    int g = l >> 4;
    int ln = l & 15;
    int h = blockIdx.x >> 8;
    int qt = (blockIdx.x & 255) * 16;
    const u16* qh = qws + h * 131072;
    const u16* kh = kws + h * 131072;
    const u16* vh = vtws + h * 131072;
    int j0 = wid * 512;

    s8v aq = *(const s8v*)(qh + (qt + ln) * 32 + 8 * g);
    f4v zero = {0.f, 0.f, 0.f, 0.f};

    // three phase-disjoint views of the same LDS (barrier-separated)
    __shared__ __align__(16) union SmemU {
        float red[8][16];          // pass A: per-wave partial row sums (512 B)
        float sT[2][16][260];      // pass B: dbuf 16 q-rows x 256 cols (+4 pad)
        float pctx[8][16][32];     // final: per-wave ctx partials (16 KB)
    } sm;

    // ---- pass A: row sums only ----
    f4v lacc = zero;
    for (int jc = 0; jc < 16; ++jc) {
        int jb = j0 + jc * 32;
        s8v b0 = *(const s8v*)(kh + (jb + ln) * 32 + 8 * g);
        s8v b1 = *(const s8v*)(kh + (jb + 16 + ln) * 32 + 8 * g);
        f4v S0 = MFMA16(aq, b0, zero);
        f4v S1 = MFMA16(aq, b1, zero);
#pragma unroll
        for (int r = 0; r < 4; ++r)
            lacc[r] += __expf(S0[r]) + __expf(S1[r]);
    }
#pragma unroll
    for (int m = 1; m <= 8; m <<= 1) {
        lacc[0] += __shfl_xor(lacc[0], m);
        lacc[1] += __shfl_xor(lacc[1], m);
        lacc[2] += __shfl_xor(lacc[2], m);
        lacc[3] += __shfl_xor(lacc[3], m);
    }
    if (ln == 0) {
#pragma unroll
        for (int r = 0; r < 4; ++r) sm.red[wid][4 * g + r] = lacc[r];
    }
    __syncthreads();
    // per-lane normalizer for q-row (qt + ln)
    float linvq = 1.f / (sm.red[0][ln] + sm.red[1][ln] + sm.red[2][ln] + sm.red[3][ln] +
                         sm.red[4][ln] + sm.red[5][ln] + sm.red[6][ln] + sm.red[7][ln]);
    __syncthreads();   // red fully consumed; sT may now be written

    // ---- pass B: dbuf transpose store + PV from sT ----
    float* attnh = attn + (size_t)h * 4096 * 4096;
    f4v accA = zero, accB = zero;   // ctx partials over this wave's col slices
    int co = wid * 32;
    auto COMPUTE = [&](int c, int p) {
        int jb = c * 256 + co;
        s8v b0 = *(const s8v*)(kh + (jb + ln) * 32 + 8 * g);
        s8v b1 = *(const s8v*)(kh + (jb + 16 + ln) * 32 + 8 * g);
        // swapped: D[k_local = 4g+r][q = ln]; reg quad = 4 consecutive k
        f4v S0 = MFMA16(b0, aq, zero);
        f4v S1 = MFMA16(b1, aq, zero);
        f4v o0, o1;
#pragma unroll
        for (int r = 0; r < 4; ++r) {
            o0[r] = __expf(S0[r]) * linvq;
            o1[r] = __expf(S1[r]) * linvq;
        }
        *(f4v*)&sm.sT[p][ln][co + 4 * g] = o0;
        *(f4v*)&sm.sT[p][ln][co + 16 + 4 * g] = o1;
    };
    auto PVSTORE = [&](int c, int p) {
        int jb = c * 256 + co;
        // PV over this wave's 32-col slice: bp = P[q=ln][k=co+8g..+7] (normalized)
        f4v t0 = *(const f4v*)&sm.sT[p][ln][co + 8 * g];
        f4v t1 = *(const f4v*)&sm.sT[p][ln][co + 8 * g + 4];
        union { u16 u[8]; s8v v; } bp;
#pragma unroll
        for (int i = 0; i < 4; ++i) { bp.u[i] = f2bf(t0[i]); bp.u[4 + i] = f2bf(t1[i]); }
        s8v va = *(const s8v*)(vh + ln * 4096 + jb + 8 * g);
        s8v vb = *(const s8v*)(vh + (16 + ln) * 4096 + jb + 8 * g);
        accA = MFMA16(va, bp.v, accA);
        accB = MFMA16(vb, bp.v, accB);
        // store: wave stores rows {2wid, 2wid+1}, 1KB contiguous each
#pragma unroll
        for (int r2 = 0; r2 < 2; ++r2) {
            int row = 2 * wid + r2;
            f4v t = *(const f4v*)&sm.sT[p][row][4 * l];
            *(f4v*)(attnh + (size_t)(qt + row) * 4096 + c * 256 + 4 * l) = t;
        }
    };
    COMPUTE(0, 0);
    __syncthreads();
    for (int c = 1; c < 16; ++c) {
        PVSTORE(c - 1, (c - 1) & 1);
        COMPUTE(c, c & 1);
        __syncthreads();
    }
    PVSTORE(15, 1);
    __syncthreads();   // all sT reads done; pctx region may now be written

    // ---- cross-wave ctx reduce (already normalized) ----
#pragma unroll
    for (int r = 0; r < 4; ++r) {
        sm.pctx[wid][ln][4 * g + r] = accA[r];
        sm.pctx[wid][ln][16 + 4 * g + r] = accB[r];
    }
    __syncthreads();
    {
        int q = tid >> 5;          // 0..15
        int d = tid & 31;          // 0..31
        float s = sm.pctx[0][q][d] + sm.pctx[1][q][d] + sm.pctx[2][q][d] + sm.pctx[3][q][d] +
                  sm.pctx[4][q][d] + sm.pctx[5][q][d] + sm.pctx[6][q][d] + sm.pctx[7][q][d];
        ctxws[(size_t)(qt + q) * 128 + h * 32 + d] = s;
    }
}

// ======================= K5: wo + LayerNorm + task + op_in (LDS weights; one barrier) =======================
__global__ __launch_bounds__(512) void k5_post(
    const float* __restrict__ ctxws, const float* __restrict__ tactws,
    const float* __restrict__ wo, const float* __restrict__ bo,
    const float* __restrict__ lng, const float* __restrict__ lnb,
    const float* __restrict__ taw1, const float* __restrict__ tab1,
    const float* __restrict__ taw2, const float* __restrict__ tab2,
    const float* __restrict__ as, float* __restrict__ dout, u16* __restrict__ opin) {
    __shared__ float wos[128 * 128];
    __shared__ float tw1s[128 * 64];
    __shared__ float tw2s[64 * 32];
    __shared__ float cx[8][128];       // wave-private
    __shared__ float coords[8][128];   // wave-private
    __shared__ float t1v[8][64];       // wave-private
    int tid = threadIdx.x;
    for (int i = tid; i < 128 * 128; i += 512) wos[i] = wo[i];
    for (int i = tid; i < 128 * 64; i += 512) tw1s[i] = taw1[i];
    for (int i = tid; i < 64 * 32; i += 512) tw2s[i] = taw2[i];
    __syncthreads();   // only barrier: weight staging
    int w = tid >> 6, l = tid & 63;
    for (int it = 0; it < 2; ++it) {
        int n = blockIdx.x * 16 + w * 2 + it;
        float c0 = ctxws[(size_t)n * 128 + l], c1 = ctxws[(size_t)n * 128 + 64 + l];
        float t0 = tactws[(size_t)n * 128 + l], t1 = tactws[(size_t)n * 128 + 64 + l];
        float av = as[n * 64 + l];
        cx[w][l] = c0; cx[w][64 + l] = c1;   // same-wave LDS roundtrip: in-order
        float r0 = bo[l] + t0, r1 = bo[64 + l] + t1;
        for (int k = 0; k < 128; ++k) {
            float cv = cx[w][k];
            r0 += cv * wos[k * 128 + l];
            r1 += cv * wos[k * 128 + 64 + l];
        }
        float s = r0 + r1;
#pragma unroll
        for (int m = 1; m <= 32; m <<= 1) s += __shfl_xor(s, m);
        float mu = s * (1.f / 128.f);
        float d0 = r0 - mu, d1 = r1 - mu;
        float vs = d0 * d0 + d1 * d1;
#pragma unroll
        for (int m = 1; m <= 32; m <<= 1) vs += __shfl_xor(vs, m);
        float rstd = 1.f / sqrtf(vs * (1.f / 128.f) + EPSV);
        float co0 = d0 * rstd * lng[l] + lnb[l];
        float co1 = d1 * rstd * lng[64 + l] + lnb[64 + l];
        coords[w][l] = co0; coords[w][64 + l] = co1;
        opin[(size_t)n * 224 + l] = f2bf(av);
        opin[(size_t)n * 224 + 64 + l] = f2bf(co0);
        opin[(size_t)n * 224 + 128 + l] = f2bf(co1);
        float a1 = tab1[l];
        for (int i = 0; i < 128; ++i) a1 += coords[w][i] * tw1s[i * 64 + l];
        t1v[w][l] = fmaxf(a1, 0.f);
        if (l < 32) {
            float a2 = tab2[l];
            for (int i = 0; i < 64; ++i) a2 += t1v[w][i] * tw2s[i * 32 + l];
            float mx = a2;
#pragma unroll
            for (int m = 1; m <= 16; m <<= 1) mx = fmaxf(mx, __shfl_xor(mx, m));
            float e = __expf(a2 - mx);
            float se = e;
#pragma unroll
            for (int m = 1; m <= 16; m <<= 1) se += __shfl_xor(se, m);
            float tk = e / se;
            dout[OFF_TASK + n * 32 + l] = tk;
            opin[(size_t)n * 224 + 192 + l] = f2bf(tk);
        }
    }
}

// ======================= K6a: H = relu(opin @ ow1 + ob1), bf16 MFMA =======================
__global__ __launch_bounds__(256) void k6a(const u16* __restrict__ opin, const u16* __restrict__ w1t,
                                           const float* __restrict__ ob1, u16* __restrict__ Hws) {
    int tid = threadIdx.x;
    int w = tid >> 6, l = tid & 63, g = l >> 4, ln = l & 15;
    int bm = blockIdx.x & 63, bn = blockIdx.x >> 6;
    int m0 = bm * 64 + w * 16, n0 = bn * 64;
    f4v acc[4];
    f4v zero = {0.f, 0.f, 0.f, 0.f};
#pragma unroll
    for (int nt = 0; nt < 4; ++nt) acc[nt] = zero;
    for (int kt = 0; kt < 7; ++kt) {
        s8v A = *(const s8v*)(opin + (size_t)(m0 + ln) * 224 + kt * 32 + 8 * g);
#pragma unroll
        for (int nt = 0; nt < 4; ++nt) {
            s8v B = *(const s8v*)(w1t + (size_t)(n0 + nt * 16 + ln) * 224 + kt * 32 + 8 * g);
            acc[nt] = MFMA16(A, B, acc[nt]);
        }
    }
#pragma unroll
    for (int nt = 0; nt < 4; ++nt) {
        int col = n0 + nt * 16 + ln;
        float bias = ob1[col];
#pragma unroll
        for (int r = 0; r < 4; ++r) {
            int row = m0 + 4 * g + r;
            Hws[(size_t)row * 256 + col] = f2bf(fmaxf(acc[nt][r] + bias, 0.f));
        }
    }
}

// ======================= K6b: opf = relu(H @ ow2 + ob2) =======================
__global__ __launch_bounds__(256) void k6b(const u16* __restrict__ Hws, const u16* __restrict__ w2t,
                                           const float* __restrict__ ob2, u16* __restrict__ opfws) {
    int tid = threadIdx.x;
    int w = tid >> 6, l = tid & 63, g = l >> 4, ln = l & 15;
    int bm = blockIdx.x & 63, bn = blockIdx.x >> 6;
    int m0 = bm * 64 + w * 16, n0 = bn * 64;
    f4v acc[4];
    f4v zero = {0.f, 0.f, 0.f, 0.f};
#pragma unroll
    for (int nt = 0; nt < 4; ++nt) acc[nt] = zero;
    for (int kt = 0; kt < 8; ++kt) {
        s8v A = *(const s8v*)(Hws + (size_t)(m0 + ln) * 256 + kt * 32 + 8 * g);
#pragma unroll
        for (int nt = 0; nt < 4; ++nt) {
            s8v B = *(const s8v*)(w2t + (size_t)(n0 + nt * 16 + ln) * 256 + kt * 32 + 8 * g);
            acc[nt] = MFMA16(A, B, acc[nt]);
        }
    }
#pragma unroll
    for (int nt = 0; nt < 4; ++nt) {
        int col = n0 + nt * 16 + ln;
        float bias = ob2[col];
#pragma unroll
        for (int r = 0; r < 4; ++r) {
            int row = m0 + 4 * g + r;
            opfws[(size_t)row * 128 + col] = f2bf(fmaxf(acc[nt][r] + bias, 0.f));
        }
    }
}

// ======================= K6c: actions / values / messages =======================
__global__ __launch_bounds__(256) void k6c(const u16* __restrict__ opf, const float* __restrict__ as,
                                           const float* __restrict__ aw, const float* __restrict__ ab,
                                           const float* __restrict__ vw, const float* __restrict__ vb,
                                           const float* __restrict__ cw, const float* __restrict__ cb,
                                           const float* __restrict__ cdw, const float* __restrict__ cdb,
                                           float* __restrict__ dout) {
    __shared__ float opfs[4][128];
    __shared__ float asl[4][64];
    __shared__ float m1s[4][64];
    int tid = threadIdx.x;
    int w = tid >> 6, l = tid & 63;
    int n = blockIdx.x * 4 + w;
    {
        u32 u = *(const u32*)(opf + (size_t)n * 128 + 2 * l);
        opfs[w][2 * l] = bf2f((u16)(u & 0xffff));
        opfs[w][2 * l + 1] = bf2f((u16)(u >> 16));
        asl[w][l] = as[n * 64 + l];
    }
    __syncthreads();
    if (l < 32) {
        float a = ab[l];
        for (int k = 0; k < 128; ++k) a += opfs[w][k] * aw[k * 32 + l];
        dout[OFF_ACT + n * 32 + l] = a;
    }
    {
        float p = opfs[w][l] * vw[l] + opfs[w][64 + l] * vw[64 + l];
#pragma unroll
        for (int m = 1; m <= 32; m <<= 1) p += __shfl_xor(p, m);
        if (l == 0) dout[OFF_VAL + n] = p + vb[0];
    }
    {
        float a = cb[l];
        for (int k = 0; k < 64; ++k) a += asl[w][k] * cw[k * 64 + l];
        m1s[w][l] = a;
    }
    __syncthreads();
    if (l < 32) {
        float a = cdb[l];
        for (int k = 0; k < 64; ++k) a += m1s[w][k] * cdw[k * 32 + l];
        dout[OFF_MSG + n * 32 + l] = a;
    }
}

// ======================= launch =======================
extern "C" void kernel_launch(void* const* d_in, const int* in_sizes, int n_in,
                              void* d_out, int out_size, void* d_ws, size_t ws_size,
                              hipStream_t stream) {
    const float* as  = (const float*)d_in[0];
    const float* sw1 = (const float*)d_in[1];
    const float* sb1 = (const float*)d_in[2];
    const float* sw2 = (const float*)d_in[3];
    const float* sb2 = (const float*)d_in[4];
    const float* sow = (const float*)d_in[5];
    const float* sob = (const float*)d_in[6];
    const float* tw  = (const float*)d_in[7];
    const float* tb  = (const float*)d_in[8];
    const float* wq  = (const float*)d_in[9];
    const float* bq  = (const float*)d_in[10];
    const float* wk  = (const float*)d_in[11];
    const float* bk  = (const float*)d_in[12];
    const float* wv  = (const float*)d_in[13];
    const float* bv  = (const float*)d_in[14];
    const float* wo  = (const float*)d_in[15];
    const float* bo  = (const float*)d_in[16];
    const float* lng = (const float*)d_in[17];
    const float* lnb = (const float*)d_in[18];
    const float* taw1 = (const float*)d_in[19];
    const float* tab1 = (const float*)d_in[20];
    const float* taw2 = (const float*)d_in[21];
    const float* tab2 = (const float*)d_in[22];
    const float* ow1 = (const float*)d_in[23];
    const float* ob1 = (const float*)d_in[24];
    const float* ow2 = (const float*)d_in[25];
    const float* ob2 = (const float*)d_in[26];
    const float* aw  = (const float*)d_in[27];
    const float* ab  = (const float*)d_in[28];
    const float* vw  = (const float*)d_in[29];
    const float* vb  = (const float*)d_in[30];
    const float* cw  = (const float*)d_in[31];
    const float* cb  = (const float*)d_in[32];
    const float* cdw = (const float*)d_in[33];
    const float* cdb = (const float*)d_in[34];

    float* dout = (float*)d_out;
    char* ws = (char*)d_ws;
    float* p1    = (float*)(ws + WS_P1);
    float* p1b   = (float*)(ws + WS_P1B);
    float* p2    = (float*)(ws + WS_P2);
    float* tactw = (float*)(ws + WS_TACT);
    u16*   qws   = (u16*)(ws + WS_Q);
    u16*   kws   = (u16*)(ws + WS_K);
    u16*   vtws  = (u16*)(ws + WS_VT);
    float* ctxws = (float*)(ws + WS_CTX);
    u16*   opin  = (u16*)(ws + WS_OPIN);
    u16*   Hws   = (u16*)(ws + WS_H);
    u16*   opfws = (u16*)(ws + WS_OPF);
    u16*   w1t   = (u16*)(ws + WS_OW1T);
    u16*   w2t   = (u16*)(ws + WS_OW2T);

    hipLaunchKernelGGL(k1_sw1, dim3(768), dim3(256), 0, stream, as, sw1, p1, ow1, ow2, w1t, w2t);
    hipLaunchKernelGGL(k1b_red, dim3(16), dim3(256), 0, stream, p1, p1b);
    hipLaunchKernelGGL(k2b_strat, dim3(16), dim3(256), 0, stream, p1b, sb1, sw2, p2);
    hipLaunchKernelGGL(k3_tact_qkv, dim3(512), dim3(256), 0, stream,
                       p2, sb2, sow, sob, as, tw, tb, wq, bq, wk, bk, wv, bv,
                       dout + OFF_GOBJ, tactw, qws, kws, vtws);
    hipLaunchKernelGGL(k4_attn, dim3(1024), dim3(512), 0, stream,
                       qws, kws, vtws, dout + OFF_ATTN, ctxws);
    hipLaunchKernelGGL(k5_post, dim3(256), dim3(512), 0, stream,
                       ctxws, tactw, wo, bo, lng, lnb, taw1, tab1, taw2, tab2, as, dout, opin);
    hipLaunchKernelGGL(k6a, dim3(256), dim3(256), 0, stream, opin, w1t, ob1, Hws);
    hipLaunchKernelGGL(k6b, dim3(128), dim3(256), 0, stream, Hws, w2t, ob2, opfws);
    hipLaunchKernelGGL(k6c, dim3(1024), dim3(256), 0, stream,
                       opfws, as, aw, ab, vw, vb, cw, cb, cdw, cdb, dout);
}